// Round 2
// baseline (859.511 us; speedup 1.0000x reference)
//
#include <hip/hip_runtime.h>
#include <hip/hip_bf16.h>

#define B_TRIPLES 1024
#define N_ENT 100000
#define RANK 256
#define MAX_NB 50

typedef float f32x4 __attribute__((ext_vector_type(4)));
typedef __bf16 bf16x8 __attribute__((ext_vector_type(8)));

__device__ __forceinline__ unsigned short f32_to_bf16_bits(float f) {
    unsigned u = __float_as_uint(f);
    unsigned r = ((u >> 16) & 1u) + 0x7fffu;
    return (unsigned short)((u + r) >> 16);
}

// ---------------------------------------------------------------------------
// Kernel 0: repack W_w (256x512) and W2_w (256x256) into transposed-by-4
// layout: Wt4[(j/4)*RANK + k] is a float4 = {W[k][j..j+3]}. This makes the
// per-triple matvec loads fully coalesced (16B/lane, lanes contiguous).
// ---------------------------------------------------------------------------
__global__ __launch_bounds__(256) void prep_kernel(
    const float* __restrict__ W_w, const float* __restrict__ W2_w,
    float* __restrict__ Wt4, float* __restrict__ W2t4)
{
    int t = blockIdx.x * 256 + threadIdx.x;           // 0..196607
    if (t < RANK * 2 * RANK) {                        // 131072
        int k = t >> 9, j = t & 511;                  // read coalesced over j
        Wt4[((j >> 2) * RANK + k) * 4 + (j & 3)] = W_w[t];
    } else {
        int u = t - RANK * 2 * RANK;                  // 0..65535
        int k = u >> 8, j = u & 255;
        W2t4[((j >> 2) * RANK + k) * 4 + (j & 3)] = W2_w[u];
    }
}

// ---------------------------------------------------------------------------
// Kernel 1: one block per triple. No neighbor LDS staging (rhs_w is
// LLC-resident; staging cost occupancy). Weight matvecs read the repacked
// transposed layout (coalesced).
// ---------------------------------------------------------------------------
__global__ __launch_bounds__(256) void triple_kernel(
    const int* __restrict__ x, const int* __restrict__ nb_idx,
    const float* __restrict__ lhs_w, const float* __restrict__ rel_w,
    const float* __restrict__ rhs_w,
    const float* __restrict__ Wt4, const float* __restrict__ W_b,
    const float* __restrict__ W2t4, const float* __restrict__ W2_b,
    const float* __restrict__ Wo_w, const float* __restrict__ Wo_b,
    const float* __restrict__ Uo_w, const float* __restrict__ Uo_b,
    float* __restrict__ out_tail, unsigned short* __restrict__ qb)
{
    __shared__ float trp[2 * RANK];          // [lhs | rel], later reused as ec_pre
    __shared__ float w_s[RANK];
    __shared__ float alpha_s[MAX_NB];
    __shared__ int   nbrow[MAX_NB];
    __shared__ float red[8];

    const int b    = blockIdx.x;
    const int k    = threadIdx.x;     // 0..255
    const int lane = k & 63;
    const int wv   = k >> 6;

    const int i0 = x[b * 3 + 0];
    const int i1 = x[b * 3 + 1];
    const int i2 = x[b * 3 + 2];

    const float lhs  = lhs_w[(size_t)i0 * RANK + k];
    const float rel  = rel_w[(size_t)i1 * RANK + k];
    const float rhsv = rhs_w[(size_t)i2 * RANK + k];

    out_tail[0 * B_TRIPLES * RANK + b * RANK + k] = lhs;
    out_tail[1 * B_TRIPLES * RANK + b * RANK + k] = rel;
    out_tail[2 * B_TRIPLES * RANK + b * RANK + k] = rhsv;

    trp[k]        = lhs;
    trp[RANK + k] = rel;
    if (k < MAX_NB) nbrow[k] = nb_idx[b * MAX_NB + k];
    __syncthreads();

    // w[k] = W_b[k] + sum_j W_w[k,j]*trp[j], via transposed-by-4 layout:
    // load float4 {W[k][4jc..4jc+3]} at Wt4[jc*RANK + k]  (coalesced)
    float acc = W_b[k];
    {
        const float4* Wp = (const float4*)Wt4;
        #pragma unroll 8
        for (int jc = 0; jc < (2 * RANK) / 4; ++jc) {
            float4 wv4 = Wp[jc * RANK + k];
            float4 t   = *(const float4*)&trp[jc * 4];
            acc += wv4.x * t.x + wv4.y * t.y + wv4.z * t.z + wv4.w * t.w;
        }
    }
    w_s[k] = acc;
    __syncthreads();

    // scores[m] = <w, rhs_w[nbrow[m]]>, one wave per m (round-robin),
    // float4 per lane (64 lanes * 4 = 256 = RANK)
    for (int m = wv; m < MAX_NB; m += 4) {
        const float* nrow = rhs_w + (size_t)nbrow[m] * RANK;
        float4 nv  = *(const float4*)(nrow + lane * 4);
        float4 wv4 = *(const float4*)(w_s + lane * 4);
        float p = nv.x * wv4.x + nv.y * wv4.y + nv.z * wv4.z + nv.w * wv4.w;
        #pragma unroll
        for (int off = 32; off > 0; off >>= 1) p += __shfl_down(p, off);
        if (lane == 0) alpha_s[m] = p;
    }
    __syncthreads();

    // softmax over 50 (wave 0)
    if (wv == 0) {
        float v = (lane < MAX_NB) ? alpha_s[lane] : -1e30f;
        float mx = v;
        #pragma unroll
        for (int off = 1; off < 64; off <<= 1) mx = fmaxf(mx, __shfl_xor(mx, off));
        float e = (lane < MAX_NB) ? __expf(v - mx) : 0.f;
        float s = e;
        #pragma unroll
        for (int off = 1; off < 64; off <<= 1) s += __shfl_xor(s, off);
        if (lane < MAX_NB) alpha_s[lane] = e / s;
    }
    __syncthreads();

    // ec_pre[k] = sum_m alpha[m] * rhs_w[nbrow[m], k]   (coalesced rows)
    float ecp = 0.f;
    #pragma unroll 5
    for (int m = 0; m < MAX_NB; ++m)
        ecp += alpha_s[m] * rhs_w[(size_t)nbrow[m] * RANK + k];
    trp[k] = ecp;                    // reuse trp[0..255] as ec_pre
    __syncthreads();

    // e_c[k] = W2_b[k] + sum_j W2_w[k,j]*ec_pre[j]  (transposed-by-4 layout)
    float ec = W2_b[k];
    {
        const float4* W2p = (const float4*)W2t4;
        #pragma unroll 8
        for (int jc = 0; jc < RANK / 4; ++jc) {
            float4 wv4 = W2p[jc * RANK + k];
            float4 t   = *(const float4*)&trp[jc * 4];
            ec += wv4.x * t.x + wv4.y * t.y + wv4.z * t.z + wv4.w * t.w;
        }
    }
    out_tail[3 * B_TRIPLES * RANK + b * RANK + k] = ec;

    // g = sigmoid(<lhs*rel, Uo> + Uo_b + <e_c, Wo> + Wo_b)
    float part = lhs * rel * Uo_w[k] + ec * Wo_w[k];
    #pragma unroll
    for (int off = 32; off > 0; off >>= 1) part += __shfl_down(part, off);
    if (lane == 0) red[wv] = part;
    __syncthreads();
    if (k == 0) {
        float s = red[0] + red[1] + red[2] + red[3] + Uo_b[0] + Wo_b[0];
        red[4] = 1.f / (1.f + __expf(-s));
    }
    __syncthreads();
    const float g = red[4];
    const float gated = g * ec + (1.f - g);
    qb[b * RANK + k] = f32_to_bf16_bits(lhs * rel * gated);
}

// ---------------------------------------------------------------------------
// Kernel 2: tot_forward[b,e] = sum_k q[b,k] * rhs[e,k] via bf16 MFMA 16x16x32.
// B-operand read DIRECTLY from rhs_w (f32) and converted to bf16 in-register
// (same RNE bit-trick as before -> bit-identical results). This removes the
// separate cvt kernel and its 153.6 MB of HBM traffic; the gemm has ~3x
// compute headroom so the inline cvt hides under the memory streams.
// 1D grid of 3126 with bijective XCD-chunk swizzle: the two b-halves of each
// e-tile are adjacent in swz -> same XCD -> the f32 B-tile (128 KB << 4 MiB
// L2) is fetched from HBM once, hit in L2 the second time.
// Output stores are non-temporal: the 409.6 MB write stream must not evict
// the shared B-tiles from L2 between the paired blocks.
// A-frag: lane holds A[m=lane&15][k=quad*8+j]; B-frag: B[k=quad*8+j][n=lane&15].
// C/D: col = lane&15, row = quad*4 + reg   [m89/m91 verified mapping]
// ---------------------------------------------------------------------------
__global__ __launch_bounds__(512) void gemm_kernel(
    const float* __restrict__ rhs_w,
    const unsigned short* __restrict__ qb,
    float* __restrict__ out)
{
    const int lane = threadIdx.x & 63;
    const int wv   = threadIdx.x >> 6;
    const int r    = lane & 15;
    const int quad = lane >> 4;

    // bijective XCD-chunk swizzle, nwg = 3126 = 8*390 + 6
    const int bid = blockIdx.x;
    constexpr int Q = 390, R = 6;
    const int xcd = bid & 7, off = bid >> 3;
    const int swz = (xcd < R ? xcd * (Q + 1) : R * (Q + 1) + (xcd - R) * Q) + off;

    const int e_blk  = (swz >> 1) * 64;
    const int b_base = (swz & 1) * 512 + wv * 64;

    f32x4 acc[4][4] = {};

    #pragma unroll
    for (int kt = 0; kt < 8; ++kt) {
        const int ko = kt * 32 + quad * 8;
        union { uint4 u; bf16x8 v; } a[4], bb[4];
        #pragma unroll
        for (int tm = 0; tm < 4; ++tm) {
            const int brow = b_base + tm * 16 + r;
            a[tm].u = *(const uint4*)(qb + (size_t)brow * RANK + ko);
        }
        #pragma unroll
        for (int tn = 0; tn < 4; ++tn) {
            int e = e_blk + tn * 16 + r;
            if (e >= N_ENT) e = N_ENT - 1;      // clamp; store is guarded
            const float4* pr = (const float4*)(rhs_w + (size_t)e * RANK + ko);
            float4 b0 = pr[0], b1 = pr[1];
            bb[tn].u.x = (unsigned)f32_to_bf16_bits(b0.x) | ((unsigned)f32_to_bf16_bits(b0.y) << 16);
            bb[tn].u.y = (unsigned)f32_to_bf16_bits(b0.z) | ((unsigned)f32_to_bf16_bits(b0.w) << 16);
            bb[tn].u.z = (unsigned)f32_to_bf16_bits(b1.x) | ((unsigned)f32_to_bf16_bits(b1.y) << 16);
            bb[tn].u.w = (unsigned)f32_to_bf16_bits(b1.z) | ((unsigned)f32_to_bf16_bits(b1.w) << 16);
        }
        #pragma unroll
        for (int tm = 0; tm < 4; ++tm)
            #pragma unroll
            for (int tn = 0; tn < 4; ++tn)
                acc[tm][tn] = __builtin_amdgcn_mfma_f32_16x16x32_bf16(
                    a[tm].v, bb[tn].v, acc[tm][tn], 0, 0, 0);
    }

    #pragma unroll
    for (int tm = 0; tm < 4; ++tm) {
        #pragma unroll
        for (int i = 0; i < 4; ++i) {
            const int brow = b_base + tm * 16 + quad * 4 + i;
            float* orow = out + (size_t)brow * N_ENT;
            #pragma unroll
            for (int tn = 0; tn < 4; ++tn) {
                const int e = e_blk + tn * 16 + r;
                if (e < N_ENT)
                    __builtin_nontemporal_store(acc[tm][tn][i], &orow[e]);
            }
        }
    }
}

// ---------------------------------------------------------------------------
extern "C" void kernel_launch(void* const* d_in, const int* in_sizes, int n_in,
                              void* d_out, int out_size, void* d_ws, size_t ws_size,
                              hipStream_t stream)
{
    const int*   x     = (const int*)d_in[0];
    const int*   nb    = (const int*)d_in[1];
    const float* lhs_w = (const float*)d_in[2];
    const float* rel_w = (const float*)d_in[3];
    const float* rhs_w = (const float*)d_in[4];
    const float* W_w   = (const float*)d_in[5];
    const float* W_b   = (const float*)d_in[6];
    const float* W2_w  = (const float*)d_in[7];
    const float* W2_b  = (const float*)d_in[8];
    const float* Wo_w  = (const float*)d_in[9];
    const float* Wo_b  = (const float*)d_in[10];
    const float* Uo_w  = (const float*)d_in[11];
    const float* Uo_b  = (const float*)d_in[12];

    float* out      = (float*)d_out;
    float* out_tail = out + (size_t)B_TRIPLES * N_ENT;

    unsigned short* qb = (unsigned short*)d_ws;                   // 512 KB
    float* Wt4  = (float*)(qb + (size_t)B_TRIPLES * RANK);        // +512 KB
    float* W2t4 = Wt4 + (size_t)(2 * RANK) * RANK;                // +256 KB

    // (131072 + 65536) / 256 = 768 blocks
    prep_kernel<<<768, 256, 0, stream>>>(W_w, W2_w, Wt4, W2t4);

    triple_kernel<<<B_TRIPLES, 256, 0, stream>>>(
        x, nb, lhs_w, rel_w, rhs_w, Wt4, W_b, W2t4, W2_b,
        Wo_w, Wo_b, Uo_w, Uo_b, out_tail, qb);

    gemm_kernel<<<3126, 512, 0, stream>>>(rhs_w, qb, out);

    (void)in_sizes; (void)n_in; (void)out_size; (void)ws_size;
}

// Round 3
// 672.736 us; speedup vs baseline: 1.2776x; 1.2776x over previous
//
#include <hip/hip_runtime.h>
#include <hip/hip_bf16.h>

#define B_TRIPLES 1024
#define N_ENT 100000
#define RANK 256
#define MAX_NB 50
#define N_ETILE (N_ENT / 16)   // 6250 e-tiles of 16

typedef float f32x4 __attribute__((ext_vector_type(4)));
typedef __bf16 bf16x8 __attribute__((ext_vector_type(8)));

__device__ __forceinline__ unsigned short f32_to_bf16_bits(float f) {
    unsigned u = __float_as_uint(f);
    unsigned r = ((u >> 16) & 1u) + 0x7fffu;
    return (unsigned short)((u + r) >> 16);
}
__device__ __forceinline__ unsigned pack2(float a, float b) {
    return (unsigned)f32_to_bf16_bits(a) | ((unsigned)f32_to_bf16_bits(b) << 16);
}

// ---------------------------------------------------------------------------
// Kernel 0: repack W_w (256x512) and W2_w (256x256) into transposed-by-4
// layout: Wt4[(j/4)*RANK + k] is a float4 = {W[k][j..j+3]} -> coalesced
// matvec loads in triple_kernel.
// ---------------------------------------------------------------------------
__global__ __launch_bounds__(256) void prep_kernel(
    const float* __restrict__ W_w, const float* __restrict__ W2_w,
    float* __restrict__ Wt4, float* __restrict__ W2t4)
{
    int t = blockIdx.x * 256 + threadIdx.x;           // 0..196607
    if (t < RANK * 2 * RANK) {                        // 131072
        int k = t >> 9, j = t & 511;                  // read coalesced over j
        Wt4[((j >> 2) * RANK + k) * 4 + (j & 3)] = W_w[t];
    } else {
        int u = t - RANK * 2 * RANK;                  // 0..65535
        int k = u >> 8, j = u & 255;
        W2t4[((j >> 2) * RANK + k) * 4 + (j & 3)] = W2_w[u];
    }
}

// ---------------------------------------------------------------------------
// Kernel 1: rhs_w f32 -> bf16, written in MFMA-FRAGMENT-PACKED layout:
//   unit u = (e/16)*512 + (k/8)*16 + (e%16)  holds 8 bf16 {k..k+7} of entity e.
// With this layout the gemm's B-fragment load (lane(r,quad) needs entity
// e_tile*16+r, k-group kt*4+quad) is 64 lanes x 16B CONTIGUOUS.
// One block per e-tile: coalesced row reads -> LDS (padded) -> coalesced
// packed writes. Runs first so rhs_w is L3-warm for triple_kernel's gathers.
// ---------------------------------------------------------------------------
__global__ __launch_bounds__(256) void cvt_kernel(
    const float* __restrict__ in, unsigned short* __restrict__ outp)
{
    __shared__ float lds[16 * 264];        // +8 pad per row: ds_read 4-way max
    const int tile = blockIdx.x;           // 0..6249
    const int t = threadIdx.x;
    const float4* src = (const float4*)(in + (size_t)tile * 16 * RANK);
    #pragma unroll
    for (int p = 0; p < 4; ++p) {
        int u = t + 256 * p;               // 0..1023 float4s, coalesced
        int row = u >> 6, c4 = u & 63;
        *(float4*)&lds[row * 264 + c4 * 4] = src[u];
    }
    __syncthreads();
    uint4* dst = (uint4*)outp + (size_t)tile * 512;   // 512 units per tile
    #pragma unroll
    for (int p = 0; p < 2; ++p) {
        int u2 = t + 256 * p;              // 0..511, coalesced 16B writes
        int e_local = u2 & 15, kg = u2 >> 4;
        const float* s = &lds[e_local * 264 + kg * 8];
        uint4 o;
        o.x = pack2(s[0], s[1]);
        o.y = pack2(s[2], s[3]);
        o.z = pack2(s[4], s[5]);
        o.w = pack2(s[6], s[7]);
        dst[u2] = o;
    }
}

// ---------------------------------------------------------------------------
// Kernel 2: one block per triple. No neighbor LDS staging (rhs_w is
// LLC-resident after cvt). Weight matvecs read the repacked transposed
// layout (coalesced). q output written in the same fragment-packed layout
// as rhsb so the gemm's A loads are coalesced too.
// ---------------------------------------------------------------------------
__global__ __launch_bounds__(256) void triple_kernel(
    const int* __restrict__ x, const int* __restrict__ nb_idx,
    const float* __restrict__ lhs_w, const float* __restrict__ rel_w,
    const float* __restrict__ rhs_w,
    const float* __restrict__ Wt4, const float* __restrict__ W_b,
    const float* __restrict__ W2t4, const float* __restrict__ W2_b,
    const float* __restrict__ Wo_w, const float* __restrict__ Wo_b,
    const float* __restrict__ Uo_w, const float* __restrict__ Uo_b,
    float* __restrict__ out_tail, unsigned short* __restrict__ qb)
{
    __shared__ float trp[2 * RANK];          // [lhs | rel], later reused as ec_pre
    __shared__ float w_s[RANK];
    __shared__ float alpha_s[MAX_NB];
    __shared__ int   nbrow[MAX_NB];
    __shared__ float red[8];

    const int b    = blockIdx.x;
    const int k    = threadIdx.x;     // 0..255
    const int lane = k & 63;
    const int wv   = k >> 6;

    const int i0 = x[b * 3 + 0];
    const int i1 = x[b * 3 + 1];
    const int i2 = x[b * 3 + 2];

    const float lhs  = lhs_w[(size_t)i0 * RANK + k];
    const float rel  = rel_w[(size_t)i1 * RANK + k];
    const float rhsv = rhs_w[(size_t)i2 * RANK + k];

    out_tail[0 * B_TRIPLES * RANK + b * RANK + k] = lhs;
    out_tail[1 * B_TRIPLES * RANK + b * RANK + k] = rel;
    out_tail[2 * B_TRIPLES * RANK + b * RANK + k] = rhsv;

    trp[k]        = lhs;
    trp[RANK + k] = rel;
    if (k < MAX_NB) nbrow[k] = nb_idx[b * MAX_NB + k];
    __syncthreads();

    // w[k] = W_b[k] + sum_j W_w[k,j]*trp[j]  (coalesced via Wt4)
    float acc = W_b[k];
    {
        const float4* Wp = (const float4*)Wt4;
        #pragma unroll 8
        for (int jc = 0; jc < (2 * RANK) / 4; ++jc) {
            float4 wv4 = Wp[jc * RANK + k];
            float4 t   = *(const float4*)&trp[jc * 4];
            acc += wv4.x * t.x + wv4.y * t.y + wv4.z * t.z + wv4.w * t.w;
        }
    }
    w_s[k] = acc;
    __syncthreads();

    // scores[m] = <w, rhs_w[nbrow[m]]>, one wave per m (round-robin)
    for (int m = wv; m < MAX_NB; m += 4) {
        const float* nrow = rhs_w + (size_t)nbrow[m] * RANK;
        float4 nv  = *(const float4*)(nrow + lane * 4);
        float4 wv4 = *(const float4*)(w_s + lane * 4);
        float p = nv.x * wv4.x + nv.y * wv4.y + nv.z * wv4.z + nv.w * wv4.w;
        #pragma unroll
        for (int off = 32; off > 0; off >>= 1) p += __shfl_down(p, off);
        if (lane == 0) alpha_s[m] = p;
    }
    __syncthreads();

    // softmax over 50 (wave 0)
    if (wv == 0) {
        float v = (lane < MAX_NB) ? alpha_s[lane] : -1e30f;
        float mx = v;
        #pragma unroll
        for (int off = 1; off < 64; off <<= 1) mx = fmaxf(mx, __shfl_xor(mx, off));
        float e = (lane < MAX_NB) ? __expf(v - mx) : 0.f;
        float s = e;
        #pragma unroll
        for (int off = 1; off < 64; off <<= 1) s += __shfl_xor(s, off);
        if (lane < MAX_NB) alpha_s[lane] = e / s;
    }
    __syncthreads();

    // ec_pre[k] = sum_m alpha[m] * rhs_w[nbrow[m], k]   (coalesced rows)
    float ecp = 0.f;
    #pragma unroll 5
    for (int m = 0; m < MAX_NB; ++m)
        ecp += alpha_s[m] * rhs_w[(size_t)nbrow[m] * RANK + k];
    trp[k] = ecp;                    // reuse trp[0..255] as ec_pre
    __syncthreads();

    // e_c[k] = W2_b[k] + sum_j W2_w[k,j]*ec_pre[j]
    float ec = W2_b[k];
    {
        const float4* W2p = (const float4*)W2t4;
        #pragma unroll 8
        for (int jc = 0; jc < RANK / 4; ++jc) {
            float4 wv4 = W2p[jc * RANK + k];
            float4 t   = *(const float4*)&trp[jc * 4];
            ec += wv4.x * t.x + wv4.y * t.y + wv4.z * t.z + wv4.w * t.w;
        }
    }
    out_tail[3 * B_TRIPLES * RANK + b * RANK + k] = ec;

    // g = sigmoid(<lhs*rel, Uo> + Uo_b + <e_c, Wo> + Wo_b)
    float part = lhs * rel * Uo_w[k] + ec * Wo_w[k];
    #pragma unroll
    for (int off = 32; off > 0; off >>= 1) part += __shfl_down(part, off);
    if (lane == 0) red[wv] = part;
    __syncthreads();
    if (k == 0) {
        float s = red[0] + red[1] + red[2] + red[3] + Uo_b[0] + Wo_b[0];
        red[4] = 1.f / (1.f + __expf(-s));
    }
    __syncthreads();
    const float g = red[4];
    const float gated = g * ec + (1.f - g);
    // fragment-packed write: unit = (b/16)*32 + k/8 within 16-row tile, slot b%16
    qb[(((size_t)(b >> 4) * 32 + (k >> 3)) * 16 + (b & 15)) * 8 + (k & 7)] =
        f32_to_bf16_bits(lhs * rel * gated);
}

// ---------------------------------------------------------------------------
// Kernel 3: tot_forward[b,e] = sum_k q[b,k]*rhs[e,k] via bf16 MFMA 16x16x32.
// Both operands fragment-packed -> every load is 64 lanes x 16B contiguous.
// XCD-chunk swizzle keeps the two b-halves of an e-tile on the same XCD so
// the 32KB B-tile is HBM-fetched once, L2-hit the second time. Normal cached
// stores (L2 merges the 64B segments).
// A-frag: lane holds A[m=lane&15][k=quad*8+j]; B-frag: B[k=quad*8+j][n=lane&15].
// C/D: col = lane&15, row = quad*4 + reg   [m89/m91 verified mapping]
// ---------------------------------------------------------------------------
__global__ __launch_bounds__(512) void gemm_kernel(
    const unsigned short* __restrict__ rhsp,
    const unsigned short* __restrict__ qp,
    float* __restrict__ out)
{
    const int lane = threadIdx.x & 63;
    const int wv   = threadIdx.x >> 6;
    const int r    = lane & 15;
    const int quad = lane >> 4;

    // bijective XCD-chunk swizzle, nwg = 3126 = 8*390 + 6
    const int bid = blockIdx.x;
    constexpr int Q = 390, R = 6;
    const int xcd = bid & 7, off = bid >> 3;
    const int swz = (xcd < R ? xcd * (Q + 1) : R * (Q + 1) + (xcd - R) * Q) + off;

    const int et64   = swz >> 1;                     // e-tile-of-64, 0..1562
    const int b_base = (swz & 1) * 512 + wv * 64;
    const int btile  = b_base >> 4;                  // A tile-of-16 index

    f32x4 acc[4][4] = {};

    #pragma unroll
    for (int kt = 0; kt < 8; ++kt) {
        const int kq = kt * 4 + quad;                // k-group 0..31
        union { uint4 u; bf16x8 v; } a[4], bb[4];
        #pragma unroll
        for (int tm = 0; tm < 4; ++tm)
            a[tm].u = *(const uint4*)(qp + ((size_t)((btile + tm) * 32 + kq) * 16 + r) * 8);
        #pragma unroll
        for (int tn = 0; tn < 4; ++tn) {
            int etile = et64 * 4 + tn;
            if (etile >= N_ETILE) etile = N_ETILE - 1;   // clamp; store guarded
            bb[tn].u = *(const uint4*)(rhsp + ((size_t)(etile * 32 + kq) * 16 + r) * 8);
        }
        #pragma unroll
        for (int tm = 0; tm < 4; ++tm)
            #pragma unroll
            for (int tn = 0; tn < 4; ++tn)
                acc[tm][tn] = __builtin_amdgcn_mfma_f32_16x16x32_bf16(
                    a[tm].v, bb[tn].v, acc[tm][tn], 0, 0, 0);
    }

    const int e_blk = et64 * 64;
    #pragma unroll
    for (int tm = 0; tm < 4; ++tm) {
        #pragma unroll
        for (int i = 0; i < 4; ++i) {
            const int brow = b_base + tm * 16 + quad * 4 + i;
            float* orow = out + (size_t)brow * N_ENT;
            #pragma unroll
            for (int tn = 0; tn < 4; ++tn) {
                const int e = e_blk + tn * 16 + r;
                if (e < N_ENT) orow[e] = acc[tm][tn][i];
            }
        }
    }
}

// ---------------------------------------------------------------------------
extern "C" void kernel_launch(void* const* d_in, const int* in_sizes, int n_in,
                              void* d_out, int out_size, void* d_ws, size_t ws_size,
                              hipStream_t stream)
{
    const int*   x     = (const int*)d_in[0];
    const int*   nb    = (const int*)d_in[1];
    const float* lhs_w = (const float*)d_in[2];
    const float* rel_w = (const float*)d_in[3];
    const float* rhs_w = (const float*)d_in[4];
    const float* W_w   = (const float*)d_in[5];
    const float* W_b   = (const float*)d_in[6];
    const float* W2_w  = (const float*)d_in[7];
    const float* W2_b  = (const float*)d_in[8];
    const float* Wo_w  = (const float*)d_in[9];
    const float* Wo_b  = (const float*)d_in[10];
    const float* Uo_w  = (const float*)d_in[11];
    const float* Uo_b  = (const float*)d_in[12];

    float* out      = (float*)d_out;
    float* out_tail = out + (size_t)B_TRIPLES * N_ENT;

    unsigned short* rhsp = (unsigned short*)d_ws;                 // 51.2 MB
    unsigned short* qp   = rhsp + (size_t)N_ENT * RANK;           // +512 KB
    float* Wt4  = (float*)(qp + (size_t)B_TRIPLES * RANK);        // +512 KB
    float* W2t4 = Wt4 + (size_t)(2 * RANK) * RANK;                // +256 KB

    // cvt first: streams rhs_w -> L3-warm for triple_kernel's gathers
    cvt_kernel<<<N_ETILE, 256, 0, stream>>>(rhs_w, rhsp);

    // (131072 + 65536) / 256 = 768 blocks
    prep_kernel<<<768, 256, 0, stream>>>(W_w, W2_w, Wt4, W2t4);

    triple_kernel<<<B_TRIPLES, 256, 0, stream>>>(
        x, nb, lhs_w, rel_w, rhs_w, Wt4, W_b, W2t4, W2_b,
        Wo_w, Wo_b, Uo_w, Uo_b, out_tail, qp);

    gemm_kernel<<<3126, 512, 0, stream>>>(rhsp, qp, out);

    (void)in_sizes; (void)n_in; (void)out_size; (void)ws_size;
}